// Round 8
// baseline (1186.420 us; speedup 1.0000x reference)
//
#include <hip/hip_runtime.h>

// Problem constants (MyHead_67242007986918)
#define NPTS 80000      // B*NP
#define NPER 20000      // NP per batch
#define CDIM 256
#define NNB  16
#define NKP  15
#define NCLS 17
#define GSH  32
#define GSW  128

typedef __bf16 bf16x8 __attribute__((ext_vector_type(8)));
typedef float  f32x4  __attribute__((ext_vector_type(4)));

__device__ __forceinline__ unsigned short f2bf(float f){
    unsigned int u = __float_as_uint(f);
    u = u + 0x7FFFu + ((u >> 16) & 1u);     // RNE
    return (unsigned short)(u >> 16);
}
__device__ __forceinline__ unsigned int pack2(float a, float b){
    return (unsigned int)f2bf(a) | ((unsigned int)f2bf(b) << 16);
}

// ---------------- ws layout (R1-verified footprint, 124,848,128 B) ----------------
// feats  bf16 [NPTS][256]            :      0 .. 40,960,000
// kpwS   bf16 swizzled B (983040 el) : 40,960,000 .. 42,926,080
// outbuf f32  [NPTS][256]            : 42,926,080 .. 124,846,080
// stats  f32  [512] (sum, sumsq)     : 124,846,080 .. 124,848,128
#define WS_KPWT   40960000
#define WS_OUT    42926080
#define WS_STATS  124846080
#define WS_NEED   124848128

// swizzled B geometry: window (chunk c, pair P) holds K=32 = {k=2P+kwin} x {16 ch}
//  P<7 : block 8192 elems at (c*7+P)*8192 ; elem = (ctg*64 + q*16+m)*8 + j
//  P==7: block 4096 elems at 917504 + c*4096 (kwin0=k14 only); elem = (ctg*32 + (q&1)*16+m)*8 + j
#define B7_BASE 917504

__global__ void zero_stats_kernel(float* stats){ stats[threadIdx.x] = 0.f; }   // <<<1,512>>>

// Fused rearrange + bilinear grid-sample (border pad, align_corners=False) -> bf16 feats
__global__ __launch_bounds__(256) void gs_kernel(
    const float* __restrict__ x, const float* __restrict__ px,
    const float* __restrict__ py, unsigned short* __restrict__ feats)
{
    int gid = blockIdx.x * 256 + threadIdx.x;           // 80000*64 threads
    int n = gid >> 6;
    if (n >= NPTS) return;
    int c0 = (gid & 63) << 2;
    int b = n / NPER;
    float ix = fminf(fmaxf(((px[n] + 1.f) * (float)GSW - 1.f) * 0.5f, 0.f), (float)(GSW - 1));
    float iy = fminf(fmaxf(((py[n] + 1.f) * (float)GSH - 1.f) * 0.5f, 0.f), (float)(GSH - 1));
    float x0f = floorf(ix), y0f = floorf(iy);
    float wx = ix - x0f, wy = iy - y0f;
    int x0 = (int)x0f, y0 = (int)y0f;
    int x1 = min(x0 + 1, GSW - 1), y1 = min(y0 + 1, GSH - 1);
    const float* base = x + (size_t)b * (GSH * GSW * CDIM);
    float4 v00 = *(const float4*)(base + ((size_t)(y0 * GSW + x0)) * CDIM + c0);
    float4 v01 = *(const float4*)(base + ((size_t)(y0 * GSW + x1)) * CDIM + c0);
    float4 v10 = *(const float4*)(base + ((size_t)(y1 * GSW + x0)) * CDIM + c0);
    float4 v11 = *(const float4*)(base + ((size_t)(y1 * GSW + x1)) * CDIM + c0);
    float w00 = (1.f - wx) * (1.f - wy), w01 = wx * (1.f - wy);
    float w10 = (1.f - wx) * wy,         w11 = wx * wy;
    float r0 = v00.x * w00 + v01.x * w01 + v10.x * w10 + v11.x * w11;
    float r1 = v00.y * w00 + v01.y * w01 + v10.y * w10 + v11.y * w11;
    float r2 = v00.z * w00 + v01.z * w01 + v10.z * w10 + v11.z * w11;
    float r3 = v00.w * w00 + v01.w * w01 + v10.w * w10 + v11.w * w11;
    ushort4 o; o.x = f2bf(r0); o.y = f2bf(r1); o.z = f2bf(r2); o.w = f2bf(r3);
    *(ushort4*)(feats + (size_t)n * CDIM + c0) = o;
}

// kp_weights [k][c][d] f32 -> swizzled MFMA-B-fragment order (see geometry above).
// Reads coalesced; writes scatter into the L2-resident 2MB buffer.  (UNCHANGED)
__global__ __launch_bounds__(256) void wt_kernel(
    const float* __restrict__ kpw, unsigned short* __restrict__ kpwS)
{
    int gid = blockIdx.x * 256 + threadIdx.x;           // 15*65536 = 983,040 -> 3840 blocks
    int k = gid >> 16;
    int c = (gid >> 8) & 255;
    int d = gid & 255;
    unsigned short v = f2bf(kpw[gid]);
    int pair = k >> 1, kwin = k & 1, chunk = c >> 4, cl = c & 15;
    int kap = kwin * 16 + cl;                           // K-elem within window
    int q = kap >> 3, j = kap & 7;
    int m = d & 15, ctg = d >> 4;
    int idx;
    if (pair < 7) idx = (chunk * 7 + pair) * 8192 + (ctg * 64 + q * 16 + m) * 8 + j;
    else          idx = B7_BASE + chunk * 4096 + (ctg * 32 + q * 16 + m) * 8 + j;  // k=14 -> kwin0
    kpwS[idx] = v;
}

// Fused KPConv. Block = 256 thr (4 waves), 64-pt tile, 256 output channels.
// R8 = R7-verified skeleton + 2-DEEP REGISTER-STAGED GATHER replacing
// global_load_lds:
//   - rgA/rgB hold feats gathers for chunks c and c+1 (2 x 32 VGPR);
//     at chunk top the COMPILER's counted vmcnt waits only for g(c) (it
//     tracks plain loads exactly) -> g(c+1) stays in flight; regs are
//     ds_written to s_f (in-order DS pipe) then tr-read.
//   - g(c+2) issued at the old stage point (after PREFETCH_B(7)): cover
//     grows from ~300cy (R7: win6,7+barrier before vmcnt(0) drain) to
//     ~1300cy (+-: whole wf-phase) > ~900cy gather latency.
//   - chunk loop unrolled x2 so rgA/rgB indexing is static (rule #20).
// Everything else (wf-build on matrix pipe via tr_b16, hoisted B0/B1,
// parity GEMM, setprio, XOR swizzles, epilogue) identical to R7 (383us).
__global__ __launch_bounds__(256, 2) void kpconv_kernel(
    const unsigned short* __restrict__ feats,
    const unsigned short* __restrict__ kpwS,
    const int*   __restrict__ pknn,
    const float* __restrict__ pxyz,
    const float* __restrict__ kp_pts,
    float* __restrict__ outbuf,
    float* __restrict__ stats)
{
    __shared__ unsigned short s_f[16384];    // 32KB [wv4][p16][a16][c16] wave-private staging
    __shared__ unsigned short s_wf2[16384];  // 32KB [p64][k16][c16] XOR-swizzled

    int tid = threadIdx.x;
    int n0  = blockIdx.x * 64;
    int wv = tid >> 6, lane = tid & 63, m = lane & 15, q = lane >> 4;

    // ---- stager row bases: slot i covers points {2i,2i+1}; lane -> (p,a,half) ----
    int fb[8];
    {
        int pl = lane >> 5, a = (lane >> 1) & 15, half = lane & 1;
#pragma unroll
        for (int i = 0; i < 8; i++){
            int n = n0 + wv * 16 + 2 * i + pl;
            int b = n / NPER;
            fb[i] = (b * NPER + pknn[(size_t)n * NNB + a]) * CDIM + half * 8;
        }
    }

    // ---- 2-deep gather pipeline registers ----
    uint4 rgA[8], rgB[8];
#define GATHER_ISSUE(cn, R) { \
        _Pragma("unroll") \
        for (int i = 0; i < 8; i++) \
            R[i] = *(const uint4*)(feats + (size_t)(fb[i] + (cn) * 16)); }
#define STAGE_WRITE(R) { \
        _Pragma("unroll") \
        for (int i = 0; i < 8; i++) \
            *(uint4*)((char*)s_f + wv * 8192 + i * 1024 + lane * 16) = R[i]; }

    GATHER_ISSUE(0, rgA)            // latency covered by the wfrag phase below
    GATHER_ISSUE(1, rgB)

    // ---- w-fragments (B-operand of wf-MFMA): wfrag[p] = w[a=4q+j][k=m], j=0..3 ----
    // kappa-map: K-elem q*8+j <-> a=4q+j for j<4, zero for j>=4 (A and B agree).
    unsigned int wfrag[16][2];
    {
        int km = (m < 15) ? m : 14;                      // k=15 phantom -> w=0
        float kx = kp_pts[km * 3 + 0], ky = kp_pts[km * 3 + 1], kz = kp_pts[km * 3 + 2];
        int4 nb[16];
#pragma unroll
        for (int p = 0; p < 16; p++){
            int n = n0 + wv * 16 + p;
            nb[p] = *(const int4*)&pknn[(size_t)n * NNB + 4 * q];
        }
#pragma unroll
        for (int p = 0; p < 16; p++){
            int n = n0 + wv * 16 + p;
            int b = n / NPER;
            float cx = pxyz[n * 3 + 0], cy = pxyz[n * 3 + 1], cz = pxyz[n * 3 + 2];
            int gi[4] = { nb[p].x, nb[p].y, nb[p].z, nb[p].w };
            float w[4];
#pragma unroll
            for (int e = 0; e < 4; e++){
                int g = b * NPER + gi[e];
                float ex = pxyz[g * 3 + 0] - cx - kx;
                float ey = pxyz[g * 3 + 1] - cy - ky;
                float ez = pxyz[g * 3 + 2] - cz - kz;
                float d = sqrtf(ex * ex + ey * ey + ez * ez);
                w[e] = (m < 15) ? fmaxf(1.f - d * (1.f / 1.2f), 0.f) : 0.f;
            }
            wfrag[p][0] = pack2(w[0], w[1]);
            wfrag[p][1] = pack2(w[2], w[3]);
        }
    }

    f32x4 acc[4][4];
#pragma unroll
    for (int i = 0; i < 4; i++)
#pragma unroll
        for (int j = 0; j < 4; j++){ acc[i][j][0]=0.f; acc[i][j][1]=0.f; acc[i][j][2]=0.f; acc[i][j][3]=0.f; }

    // tr-b16 lane base (BYTES): contiguous-8B-per-lane + cross-lane transpose.
    // lane (q,m): byte = wv*8192 + m*8 + q*128 ; offset:p*512 walks points.
    unsigned trb;
    {
        unsigned sbase = (unsigned)(size_t)(__attribute__((address_space(3))) unsigned short*)s_f;
        trb = sbase + (unsigned)(wv * 8192 + m * 8 + q * 128);
    }
    int xr = (m & 7) << 3;                               // read-side XOR (p&7 == m&7 for p=16rt+m)

// wf-MFMA for point p: D[c=4q+r, k=m] = sum_a f[a][c]*w[a][k]; pack -> s_wf2[p][k][c]
#define WF_MFMA_PACK(p) { \
        union { uint4 u; bf16x8 v; } Af, Bw; \
        Af.u = make_uint4(tr[p].x, tr[p].y, 0u, 0u); \
        Bw.u = make_uint4(wfrag[p][0], wfrag[p][1], 0u, 0u); \
        f32x4 dz; dz[0]=0.f; dz[1]=0.f; dz[2]=0.f; dz[3]=0.f; \
        f32x4 d = __builtin_amdgcn_mfma_f32_16x16x32_bf16(Af.v, Bw.v, dz, 0, 0, 0); \
        uint2 o; o.x = pack2(d[0], d[1]); o.y = pack2(d[2], d[3]); \
        *(uint2*)&s_wf2[(((wv * 16 + (p)) * 256 + m * 16 + 4 * q)) ^ (((p) & 7) << 3)] = o; }

// GEMM window P consuming register B-buffer BREG (A-reads at prio 0, MFMAs at prio 1)
#define GEMM_WINDOW(P, BREG) { \
        bf16x8 A[4]; \
        _Pragma("unroll") \
        for (int rt = 0; rt < 4; rt++) \
            A[rt] = *(const bf16x8*)&s_wf2[(((16 * rt + m) * 256 + (2 * (P) + (q >> 1)) * 16 + (q & 1) * 8)) ^ xr]; \
        __builtin_amdgcn_s_setprio(1); \
        _Pragma("unroll") \
        for (int ct = 0; ct < 4; ct++) \
            _Pragma("unroll") \
            for (int rt = 0; rt < 4; rt++) \
                acc[rt][ct] = __builtin_amdgcn_mfma_f32_16x16x32_bf16(A[rt], BREG[ct], acc[rt][ct], 0, 0, 0); \
        __builtin_amdgcn_s_setprio(0); }

// load window Pn's B-fragments into BREG (Pn < 7: normal; Pn == 7: special block)
#define PREFETCH_B(Pn, BREG) { \
        if ((Pn) < 7){ \
            const unsigned short* bb = kpwS + (c * 7 + (Pn)) * 8192 + (q * 16 + m) * 8; \
            _Pragma("unroll") \
            for (int ct = 0; ct < 4; ct++) BREG[ct] = *(const bf16x8*)(bb + (wv * 4 + ct) * 512); \
        } else { \
            const unsigned short* bb = kpwS + B7_BASE + c * 4096 + ((q & 1) * 16 + m) * 8; \
            _Pragma("unroll") \
            for (int ct = 0; ct < 4; ct++) BREG[ct] = *(const bf16x8*)(bb + (wv * 4 + ct) * 256); \
        } }

// One chunk. R = reg set holding gather(c); refilled with gather(c+2) if DOISS.
// Compiler emits the exact counted vmcnt before STAGE_WRITE's reads of R
// (it tracks the plain gather loads) -> only g(c) is drained, g(c+1) stays
// in flight.  In-order DS pipe makes STAGE_WRITE -> tr-read safe; the ""
// memory fence + sched_barrier keep the compiler from sinking the writes.
#define CHUNK_BODY(CEXPR, R, DOISS) { \
        const int c = (CEXPR); \
        STAGE_WRITE(R) \
        asm volatile("" ::: "memory"); \
        __builtin_amdgcn_sched_barrier(0); \
        uint2 tr[16]; \
        _Pragma("unroll") \
        for (int p = 0; p < 8; p++) \
            asm volatile("ds_read_b64_tr_b16 %0, %1 offset:%2" \
                         : "=v"(tr[p]) : "v"(trb), "i"(p * 512)); \
        _Pragma("unroll") \
        for (int p = 8; p < 16; p++) \
            asm volatile("ds_read_b64_tr_b16 %0, %1 offset:%2" \
                         : "=v"(tr[p]) : "v"(trb), "i"(p * 512)); \
        asm volatile("s_waitcnt lgkmcnt(8)" ::: "memory"); \
        __builtin_amdgcn_sched_barrier(0); \
        _Pragma("unroll") \
        for (int p = 0; p < 8; p++) WF_MFMA_PACK(p) \
        asm volatile("s_waitcnt lgkmcnt(8)" ::: "memory"); \
        __builtin_amdgcn_sched_barrier(0); \
        _Pragma("unroll") \
        for (int p = 8; p < 16; p++) WF_MFMA_PACK(p) \
        bf16x8 B0[4], B1[4]; \
        PREFETCH_B(0, B0) \
        PREFETCH_B(1, B1) \
        asm volatile("s_waitcnt lgkmcnt(0)\ns_barrier" ::: "memory"); \
        GEMM_WINDOW(0, B0)  PREFETCH_B(2, B0) \
        GEMM_WINDOW(1, B1)  PREFETCH_B(3, B1) \
        GEMM_WINDOW(2, B0)  PREFETCH_B(4, B0) \
        GEMM_WINDOW(3, B1)  PREFETCH_B(5, B1) \
        GEMM_WINDOW(4, B0)  PREFETCH_B(6, B0) \
        GEMM_WINDOW(5, B1)  PREFETCH_B(7, B1) \
        if (DOISS) GATHER_ISSUE((c) + 2, R) \
        GEMM_WINDOW(6, B0) \
        GEMM_WINDOW(7, B1) \
        asm volatile("s_waitcnt lgkmcnt(0)\ns_barrier" ::: "memory"); \
    }

    for (int cc = 0; cc < 16; cc += 2){
        CHUNK_BODY(cc,     rgA, (cc < 14))
        CHUNK_BODY(cc + 1, rgB, (cc < 13))
    }
#undef CHUNK_BODY
#undef WF_MFMA_PACK
#undef GEMM_WINDOW
#undef PREFETCH_B
#undef GATHER_ISSUE
#undef STAGE_WRITE

    // ---- epilogue: store fp32, fold BN partial sums via atomics (unchanged) ----
#pragma unroll
    for (int rt = 0; rt < 4; rt++)
#pragma unroll
        for (int ct = 0; ct < 4; ct++)
#pragma unroll
            for (int r = 0; r < 4; r++){
                int prow = 16 * rt + 4 * q + r;          // C/D: row=(lane>>4)*4+r, col=lane&15
                int d = wv * 64 + ct * 16 + m;
                outbuf[(size_t)(n0 + prow) * CDIM + d] = acc[rt][ct][r];
            }
#pragma unroll
    for (int ct = 0; ct < 4; ct++){
        float s1 = 0.f, s2 = 0.f;
#pragma unroll
        for (int rt = 0; rt < 4; rt++)
#pragma unroll
            for (int r = 0; r < 4; r++){
                float v = acc[rt][ct][r];
                s1 += v; s2 += v * v;
            }
        s1 += __shfl_xor(s1, 16); s1 += __shfl_xor(s1, 32);
        s2 += __shfl_xor(s2, 16); s2 += __shfl_xor(s2, 32);
        if (q == 0){
            int d = wv * 64 + ct * 16 + m;
            atomicAdd(&stats[d], s1);
            atomicAdd(&stats[256 + d], s2);
        }
    }
}

// BN (batch stats) + ReLU + 1x1 conv head. 16 points per block.  (UNCHANGED)
__global__ __launch_bounds__(256) void head_kernel(
    const float* __restrict__ outbuf, const float* __restrict__ stats,
    const float* __restrict__ gamma,  const float* __restrict__ beta,
    const float* __restrict__ hw,     const float* __restrict__ hb,
    float* __restrict__ logits)
{
    __shared__ float s_h[16][256];
    int tid = threadIdx.x;
    int n0 = blockIdx.x * 16;
    int pt = tid >> 4, cgr = tid & 15;
    {
        int n = n0 + pt;
        const float invN = 1.f / (float)NPTS;
#pragma unroll
        for (int j = 0; j < 16; j += 4){
            int c = cgr * 16 + j;
            float4 v  = *(const float4*)(outbuf + (size_t)n * CDIM + c);
            float4 su = *(const float4*)(stats + c);
            float4 sq = *(const float4*)(stats + 256 + c);
            float4 ga = *(const float4*)(gamma + c);
            float4 be = *(const float4*)(beta + c);
            float mean, var;
            mean = su.x * invN; var = sq.x * invN - mean * mean;
            s_h[pt][c + 0] = fmaxf(ga.x * (v.x - mean) * rsqrtf(var + 1e-5f) + be.x, 0.f);
            mean = su.y * invN; var = sq.y * invN - mean * mean;
            s_h[pt][c + 1] = fmaxf(ga.y * (v.y - mean) * rsqrtf(var + 1e-5f) + be.y, 0.f);
            mean = su.z * invN; var = sq.z * invN - mean * mean;
            s_h[pt][c + 2] = fmaxf(ga.z * (v.z - mean) * rsqrtf(var + 1e-5f) + be.z, 0.f);
            mean = su.w * invN; var = sq.w * invN - mean * mean;
            s_h[pt][c + 3] = fmaxf(ga.w * (v.w - mean) * rsqrtf(var + 1e-5f) + be.w, 0.f);
        }
    }
    __syncthreads();
    for (int idx = tid; idx < 16 * NCLS; idx += 256){
        int pt2 = idx / NCLS, cls = idx - pt2 * NCLS;
        float acc = hb[cls];
#pragma unroll 8
        for (int c = 0; c < CDIM; c += 4){
            float4 h4 = *(const float4*)&s_h[pt2][c];
            float4 w4 = *(const float4*)(hw + (size_t)cls * CDIM + c);
            acc = fmaf(h4.x, w4.x, fmaf(h4.y, w4.y, fmaf(h4.z, w4.z, fmaf(h4.w, w4.w, acc))));
        }
        logits[(size_t)(n0 + pt2) * NCLS + cls] = acc;
    }
}

extern "C" void kernel_launch(void* const* d_in, const int* in_sizes, int n_in,
                              void* d_out, int out_size, void* d_ws, size_t ws_size,
                              hipStream_t stream)
{
    (void)in_sizes; (void)n_in; (void)out_size;
    if (ws_size < (size_t)WS_NEED) return;   // R1-verified footprint (119.06 MB)

    const float* x      = (const float*)d_in[0];
    // d_in[1] = skip  : dead code in reference
    const float* px     = (const float*)d_in[2];
    const float* py     = (const float*)d_in[3];
    const float* pxyz   = (const float*)d_in[4];
    const int*   pknn   = (const int*)  d_in[5];
    // d_in[6] = num_points : unused
    const float* kp_pts = (const float*)d_in[7];
    const float* kpw    = (const float*)d_in[8];
    const float* gamma  = (const float*)d_in[9];
    const float* beta   = (const float*)d_in[10];
    const float* hw     = (const float*)d_in[11];
    const float* hb     = (const float*)d_in[12];
    float* logits = (float*)d_out;

    char* ws = (char*)d_ws;
    unsigned short* feats = (unsigned short*)(ws);
    unsigned short* kpwS  = (unsigned short*)(ws + WS_KPWT);
    float* outbuf = (float*)(ws + WS_OUT);
    float* stats  = (float*)(ws + WS_STATS);

    hipLaunchKernelGGL(zero_stats_kernel, dim3(1),     dim3(512), 0, stream, stats);
    hipLaunchKernelGGL(gs_kernel,         dim3(20000), dim3(256), 0, stream, x, px, py, feats);
    hipLaunchKernelGGL(wt_kernel,         dim3(3840),  dim3(256), 0, stream, kpw, kpwS);
    hipLaunchKernelGGL(kpconv_kernel,     dim3(1250),  dim3(256), 0, stream,
                       feats, kpwS, pknn, pxyz, kp_pts, outbuf, stats);
    hipLaunchKernelGGL(head_kernel,       dim3(5000),  dim3(256), 0, stream,
                       outbuf, stats, gamma, beta, hw, hb, logits);
}

// Round 9
// 722.978 us; speedup vs baseline: 1.6410x; 1.6410x over previous
//
#include <hip/hip_runtime.h>

// Problem constants (MyHead_67242007986918)
#define NPTS 80000      // B*NP
#define NPER 20000      // NP per batch
#define CDIM 256
#define NNB  16
#define NKP  15
#define NCLS 17
#define GSH  32
#define GSW  128

typedef __bf16 bf16x8 __attribute__((ext_vector_type(8)));
typedef float  f32x4  __attribute__((ext_vector_type(4)));

__device__ __forceinline__ unsigned short f2bf(float f){
    unsigned int u = __float_as_uint(f);
    u = u + 0x7FFFu + ((u >> 16) & 1u);     // RNE
    return (unsigned short)(u >> 16);
}
__device__ __forceinline__ unsigned int pack2(float a, float b){
    return (unsigned int)f2bf(a) | ((unsigned int)f2bf(b) << 16);
}

// async global->LDS, 16B per lane; lds dest = wave-uniform base + lane*16
#define GLD_LDS16(gsrc, ldst) \
    __builtin_amdgcn_global_load_lds((const __attribute__((address_space(1))) unsigned int*)(gsrc), \
                                     (__attribute__((address_space(3))) unsigned int*)(ldst), 16, 0, 0)

// ---------------- ws layout (R1-verified footprint, 124,848,128 B) ----------------
// feats  bf16 [NPTS][256]            :      0 .. 40,960,000
// kpwS   bf16 swizzled B (983040 el) : 40,960,000 .. 42,926,080
// outbuf f32  [NPTS][256]            : 42,926,080 .. 124,846,080
// stats  f32  [512] (sum, sumsq)     : 124,846,080 .. 124,848,128
#define WS_KPWT   40960000
#define WS_OUT    42926080
#define WS_STATS  124846080
#define WS_NEED   124848128

// swizzled B geometry: window (chunk c, pair P) holds K=32 = {k=2P+kwin} x {16 ch}
//  P<7 : block 8192 elems at (c*7+P)*8192 ; elem = (ctg*64 + q*16+m)*8 + j
//  P==7: block 4096 elems at 917504 + c*4096 (kwin0=k14 only); elem = (ctg*32 + (q&1)*16+m)*8 + j
#define B7_BASE 917504

__global__ void zero_stats_kernel(float* stats){ stats[threadIdx.x] = 0.f; }   // <<<1,512>>>

// Fused rearrange + bilinear grid-sample (border pad, align_corners=False) -> bf16 feats
__global__ __launch_bounds__(256) void gs_kernel(
    const float* __restrict__ x, const float* __restrict__ px,
    const float* __restrict__ py, unsigned short* __restrict__ feats)
{
    int gid = blockIdx.x * 256 + threadIdx.x;           // 80000*64 threads
    int n = gid >> 6;
    if (n >= NPTS) return;
    int c0 = (gid & 63) << 2;
    int b = n / NPER;
    float ix = fminf(fmaxf(((px[n] + 1.f) * (float)GSW - 1.f) * 0.5f, 0.f), (float)(GSW - 1));
    float iy = fminf(fmaxf(((py[n] + 1.f) * (float)GSH - 1.f) * 0.5f, 0.f), (float)(GSH - 1));
    float x0f = floorf(ix), y0f = floorf(iy);
    float wx = ix - x0f, wy = iy - y0f;
    int x0 = (int)x0f, y0 = (int)y0f;
    int x1 = min(x0 + 1, GSW - 1), y1 = min(y0 + 1, GSH - 1);
    const float* base = x + (size_t)b * (GSH * GSW * CDIM);
    float4 v00 = *(const float4*)(base + ((size_t)(y0 * GSW + x0)) * CDIM + c0);
    float4 v01 = *(const float4*)(base + ((size_t)(y0 * GSW + x1)) * CDIM + c0);
    float4 v10 = *(const float4*)(base + ((size_t)(y1 * GSW + x0)) * CDIM + c0);
    float4 v11 = *(const float4*)(base + ((size_t)(y1 * GSW + x1)) * CDIM + c0);
    float w00 = (1.f - wx) * (1.f - wy), w01 = wx * (1.f - wy);
    float w10 = (1.f - wx) * wy,         w11 = wx * wy;
    float r0 = v00.x * w00 + v01.x * w01 + v10.x * w10 + v11.x * w11;
    float r1 = v00.y * w00 + v01.y * w01 + v10.y * w10 + v11.y * w11;
    float r2 = v00.z * w00 + v01.z * w01 + v10.z * w10 + v11.z * w11;
    float r3 = v00.w * w00 + v01.w * w01 + v10.w * w10 + v11.w * w11;
    ushort4 o; o.x = f2bf(r0); o.y = f2bf(r1); o.z = f2bf(r2); o.w = f2bf(r3);
    *(ushort4*)(feats + (size_t)n * CDIM + c0) = o;
}

// kp_weights [k][c][d] f32 -> swizzled MFMA-B-fragment order (see geometry above).
// Reads coalesced; writes scatter into the L2-resident 2MB buffer.  (UNCHANGED)
__global__ __launch_bounds__(256) void wt_kernel(
    const float* __restrict__ kpw, unsigned short* __restrict__ kpwS)
{
    int gid = blockIdx.x * 256 + threadIdx.x;           // 15*65536 = 983,040 -> 3840 blocks
    int k = gid >> 16;
    int c = (gid >> 8) & 255;
    int d = gid & 255;
    unsigned short v = f2bf(kpw[gid]);
    int pair = k >> 1, kwin = k & 1, chunk = c >> 4, cl = c & 15;
    int kap = kwin * 16 + cl;                           // K-elem within window
    int q = kap >> 3, j = kap & 7;
    int m = d & 15, ctg = d >> 4;
    int idx;
    if (pair < 7) idx = (chunk * 7 + pair) * 8192 + (ctg * 64 + q * 16 + m) * 8 + j;
    else          idx = B7_BASE + chunk * 4096 + (ctg * 32 + q * 16 + m) * 8 + j;  // k=14 -> kwin0
    kpwS[idx] = v;
}

// Fused KPConv. Block = 256 thr (4 waves), 64-pt tile, 256 output channels.
// R9 = R7-verified skeleton + 48KB LDS for 3 blocks/CU, WITHOUT the forced
// (256,3) cap that poisoned R3/R4 (compiler spilled under it):
//   - s_wf2 halved to [p64][k8][c16] (16KB); wf-pass runs twice per chunk
//     (pass h commits lanes m>>3==h at local row m&7) -- R3's exact verified
//     indexing algebra.  GEMM half h: windows P=4h..4h+3, local k'=2*Ph+(q>>1).
//   - register diet to land total (arch+AGPR) under the 3-wave/SIMD line
//     (~170): tr[16] -> tr[4] groups (4x{issue4,wait,consume4}); parity B0/B1
//     -> single B[4] direct-load per window (first window of each half hoisted
//     above the wf-ready barrier).
//   - launch_bounds stays (256,2): allocator unconstrained; HW occupancy
//     becomes 3 blocks/CU from LDS(48KB)+VGPR jointly.
// Rationale: R7 counters show ~85-90% of the measured ~2.5TB/s random-gather
// BW ceiling; more co-resident waves = more outstanding gathers = higher
// effective random BW.  4 barriers/chunk.
__global__ __launch_bounds__(256, 2) void kpconv_kernel(
    const unsigned short* __restrict__ feats,
    const unsigned short* __restrict__ kpwS,
    const int*   __restrict__ pknn,
    const float* __restrict__ pxyz,
    const float* __restrict__ kp_pts,
    float* __restrict__ outbuf,
    float* __restrict__ stats)
{
    __shared__ unsigned short s_f[16384];    // 32KB [wv4][p16][a16][c16] wave-private staging
    __shared__ unsigned short s_wf2[8192];   // 16KB [p64][k8][c16] XOR-swizzled (k half-range)

    int tid = threadIdx.x;
    int n0  = blockIdx.x * 64;
    int wv = tid >> 6, lane = tid & 63, m = lane & 15, q = lane >> 4;

    // ---- stager row bases: slot i covers points {2i,2i+1}; lane -> (p,a,half) ----
    int fb[8];
    {
        int pl = lane >> 5, a = (lane >> 1) & 15, half = lane & 1;
#pragma unroll
        for (int i = 0; i < 8; i++){
            int n = n0 + wv * 16 + 2 * i + pl;
            int b = n / NPER;
            fb[i] = (b * NPER + pknn[(size_t)n * NNB + a]) * CDIM + half * 8;
        }
    }
    // issue chunk-0 stage immediately; w-prologue below covers the DMA latency
#pragma unroll
    for (int i = 0; i < 8; i++)
        GLD_LDS16(feats + (size_t)fb[i], (char*)s_f + wv * 8192 + i * 1024);

    // ---- w-fragments (B-operand of wf-MFMA): wfrag[p] = w[a=4q+j][k=m], j=0..3 ----
    // kappa-map: K-elem q*8+j <-> a=4q+j for j<4, zero for j>=4 (A and B agree).
    unsigned int wfrag[16][2];
    {
        int km = (m < 15) ? m : 14;                      // k=15 phantom -> w=0
        float kx = kp_pts[km * 3 + 0], ky = kp_pts[km * 3 + 1], kz = kp_pts[km * 3 + 2];
        int4 nb[16];
#pragma unroll
        for (int p = 0; p < 16; p++){
            int n = n0 + wv * 16 + p;
            nb[p] = *(const int4*)&pknn[(size_t)n * NNB + 4 * q];
        }
#pragma unroll
        for (int p = 0; p < 16; p++){
            int n = n0 + wv * 16 + p;
            int b = n / NPER;
            float cx = pxyz[n * 3 + 0], cy = pxyz[n * 3 + 1], cz = pxyz[n * 3 + 2];
            int gi[4] = { nb[p].x, nb[p].y, nb[p].z, nb[p].w };
            float w[4];
#pragma unroll
            for (int e = 0; e < 4; e++){
                int g = b * NPER + gi[e];
                float ex = pxyz[g * 3 + 0] - cx - kx;
                float ey = pxyz[g * 3 + 1] - cy - ky;
                float ez = pxyz[g * 3 + 2] - cz - kz;
                float d = sqrtf(ex * ex + ey * ey + ez * ez);
                w[e] = (m < 15) ? fmaxf(1.f - d * (1.f / 1.2f), 0.f) : 0.f;
            }
            wfrag[p][0] = pack2(w[0], w[1]);
            wfrag[p][1] = pack2(w[2], w[3]);
        }
    }

    f32x4 acc[4][4];
#pragma unroll
    for (int i = 0; i < 4; i++)
#pragma unroll
        for (int j = 0; j < 4; j++){ acc[i][j][0]=0.f; acc[i][j][1]=0.f; acc[i][j][2]=0.f; acc[i][j][3]=0.f; }

    // tr-b16 lane base (BYTES): contiguous-8B-per-lane + cross-lane transpose.
    // lane (q,m): byte = wv*8192 + m*8 + q*128 ; offset:p*512 walks points.
    unsigned trb;
    {
        unsigned sbase = (unsigned)(size_t)(__attribute__((address_space(3))) unsigned short*)s_f;
        trb = sbase + (unsigned)(wv * 8192 + m * 8 + q * 128);
    }
    int xr = (m & 7) << 3;                               // read-side XOR (p&7 == m&7 for p=16rt+m)

// wf-MFMA for point p (tr slot i): D[c=4q+r, k=m] = sum_a f[a][c]*w[a][k];
// pass h commits only its k-half: lanes m>>3==h write row k'=m&7 of s_wf2[p][k8][c16]
#define WF_MFMA_PACK(p, i, h) { \
        union { uint4 u; bf16x8 v; } Af, Bw; \
        Af.u = make_uint4(tr[i].x, tr[i].y, 0u, 0u); \
        Bw.u = make_uint4(wfrag[p][0], wfrag[p][1], 0u, 0u); \
        f32x4 dz; dz[0]=0.f; dz[1]=0.f; dz[2]=0.f; dz[3]=0.f; \
        f32x4 d = __builtin_amdgcn_mfma_f32_16x16x32_bf16(Af.v, Bw.v, dz, 0, 0, 0); \
        if ((m >> 3) == (h)) { \
            uint2 o; o.x = pack2(d[0], d[1]); o.y = pack2(d[2], d[3]); \
            *(uint2*)&s_wf2[(((wv * 16 + (p)) * 128 + (m & 7) * 16 + 4 * q)) ^ (((p) & 7) << 3)] = o; } }

// GEMM window (half-local Ph) consuming single B buffer; A from 16KB s_wf2
#define GEMM_WINDOW_L(Ph, BREG) { \
        bf16x8 A[4]; \
        _Pragma("unroll") \
        for (int rt = 0; rt < 4; rt++) \
            A[rt] = *(const bf16x8*)&s_wf2[(((16 * rt + m) * 128 + (2 * (Ph) + (q >> 1)) * 16 + (q & 1) * 8)) ^ xr]; \
        __builtin_amdgcn_s_setprio(1); \
        _Pragma("unroll") \
        for (int ct = 0; ct < 4; ct++) \
            _Pragma("unroll") \
            for (int rt = 0; rt < 4; rt++) \
                acc[rt][ct] = __builtin_amdgcn_mfma_f32_16x16x32_bf16(A[rt], BREG[ct], acc[rt][ct], 0, 0, 0); \
        __builtin_amdgcn_s_setprio(0); }

// load window Pn's B-fragments into BREG (Pn < 7: normal; Pn == 7: special block)
#define PREFETCH_B(Pn, BREG) { \
        if ((Pn) < 7){ \
            const unsigned short* bb = kpwS + (c * 7 + (Pn)) * 8192 + (q * 16 + m) * 8; \
            _Pragma("unroll") \
            for (int ct = 0; ct < 4; ct++) BREG[ct] = *(const bf16x8*)(bb + (wv * 4 + ct) * 512); \
        } else { \
            const unsigned short* bb = kpwS + B7_BASE + c * 4096 + ((q & 1) * 16 + m) * 8; \
            _Pragma("unroll") \
            for (int ct = 0; ct < 4; ct++) BREG[ct] = *(const bf16x8*)(bb + (wv * 4 + ct) * 256); \
        } }

    for (int c = 0; c < 16; c++){
        asm volatile("s_waitcnt vmcnt(0)" ::: "memory");   // stage(c) landed (wave-local)

#pragma unroll
        for (int h = 0; h < 2; h++){
            // ---- wf-pass h: 4 groups of 4 tr-reads (tr[4] reused -> low reg peak) ----
#pragma unroll
            for (int g = 0; g < 4; g++){
                uint2 tr[4];
#pragma unroll
                for (int i = 0; i < 4; i++)
                    asm volatile("ds_read_b64_tr_b16 %0, %1 offset:%2"
                                 : "=v"(tr[i]) : "v"(trb), "i"((4 * g + i) * 512));
                asm volatile("s_waitcnt lgkmcnt(0)" ::: "memory");
                __builtin_amdgcn_sched_barrier(0);
#pragma unroll
                for (int i = 0; i < 4; i++) WF_MFMA_PACK(4 * g + i, i, h)
            }

            // hoisted B load for this half's first window (indep of s_wf2)
            bf16x8 B[4];
            PREFETCH_B(4 * h + 0, B)

            asm volatile("s_waitcnt lgkmcnt(0)\ns_barrier" ::: "memory");   // s_wf2[h] ready

            // ---- GEMM half h: 4 windows, single-buffer consume-then-reload ----
            GEMM_WINDOW_L(0, B)
            PREFETCH_B(4 * h + 1, B)
            GEMM_WINDOW_L(1, B)
            PREFETCH_B(4 * h + 2, B)
            GEMM_WINDOW_L(2, B)
            PREFETCH_B(4 * h + 3, B)
            // stage(c+1): issued AFTER the last B-load of the chunk (h==1) ->
            // youngest vmem ops; nothing waits on them until next chunk's
            // vmcnt(0) (in-order retire).  Cover = W(L3)+barrier; TLP (12
            // waves) hides the remainder.
            if (h == 1 && c < 15){
#pragma unroll
                for (int i = 0; i < 8; i++)
                    GLD_LDS16(feats + (size_t)(fb[i] + (c + 1) * 16), (char*)s_f + wv * 8192 + i * 1024);
            }
            GEMM_WINDOW_L(3, B)

            asm volatile("s_waitcnt lgkmcnt(0)\ns_barrier" ::: "memory");   // s_wf2[h] consumed
        }
    }
#undef WF_MFMA_PACK
#undef GEMM_WINDOW_L
#undef PREFETCH_B

    // ---- epilogue: store fp32, fold BN partial sums via atomics (unchanged) ----
#pragma unroll
    for (int rt = 0; rt < 4; rt++)
#pragma unroll
        for (int ct = 0; ct < 4; ct++)
#pragma unroll
            for (int r = 0; r < 4; r++){
                int prow = 16 * rt + 4 * q + r;          // C/D: row=(lane>>4)*4+r, col=lane&15
                int d = wv * 64 + ct * 16 + m;
                outbuf[(size_t)(n0 + prow) * CDIM + d] = acc[rt][ct][r];
            }
#pragma unroll
    for (int ct = 0; ct < 4; ct++){
        float s1 = 0.f, s2 = 0.f;
#pragma unroll
        for (int rt = 0; rt < 4; rt++)
#pragma unroll
            for (int r = 0; r < 4; r++){
                float v = acc[rt][ct][r];
                s1 += v; s2 += v * v;
            }
        s1 += __shfl_xor(s1, 16); s1 += __shfl_xor(s1, 32);
        s2 += __shfl_xor(s2, 16); s2 += __shfl_xor(s2, 32);
        if (q == 0){
            int d = wv * 64 + ct * 16 + m;
            atomicAdd(&stats[d], s1);
            atomicAdd(&stats[256 + d], s2);
        }
    }
}

// BN (batch stats) + ReLU + 1x1 conv head. 16 points per block.  (UNCHANGED)
__global__ __launch_bounds__(256) void head_kernel(
    const float* __restrict__ outbuf, const float* __restrict__ stats,
    const float* __restrict__ gamma,  const float* __restrict__ beta,
    const float* __restrict__ hw,     const float* __restrict__ hb,
    float* __restrict__ logits)
{
    __shared__ float s_h[16][256];
    int tid = threadIdx.x;
    int n0 = blockIdx.x * 16;
    int pt = tid >> 4, cgr = tid & 15;
    {
        int n = n0 + pt;
        const float invN = 1.f / (float)NPTS;
#pragma unroll
        for (int j = 0; j < 16; j += 4){
            int c = cgr * 16 + j;
            float4 v  = *(const float4*)(outbuf + (size_t)n * CDIM + c);
            float4 su = *(const float4*)(stats + c);
            float4 sq = *(const float4*)(stats + 256 + c);
            float4 ga = *(const float4*)(gamma + c);
            float4 be = *(const float4*)(beta + c);
            float mean, var;
            mean = su.x * invN; var = sq.x * invN - mean * mean;
            s_h[pt][c + 0] = fmaxf(ga.x * (v.x - mean) * rsqrtf(var + 1e-5f) + be.x, 0.f);
            mean = su.y * invN; var = sq.y * invN - mean * mean;
            s_h[pt][c + 1] = fmaxf(ga.y * (v.y - mean) * rsqrtf(var + 1e-5f) + be.y, 0.f);
            mean = su.z * invN; var = sq.z * invN - mean * mean;
            s_h[pt][c + 2] = fmaxf(ga.z * (v.z - mean) * rsqrtf(var + 1e-5f) + be.z, 0.f);
            mean = su.w * invN; var = sq.w * invN - mean * mean;
            s_h[pt][c + 3] = fmaxf(ga.w * (v.w - mean) * rsqrtf(var + 1e-5f) + be.w, 0.f);
        }
    }
    __syncthreads();
    for (int idx = tid; idx < 16 * NCLS; idx += 256){
        int pt2 = idx / NCLS, cls = idx - pt2 * NCLS;
        float acc = hb[cls];
#pragma unroll 8
        for (int c = 0; c < CDIM; c += 4){
            float4 h4 = *(const float4*)&s_h[pt2][c];
            float4 w4 = *(const float4*)(hw + (size_t)cls * CDIM + c);
            acc = fmaf(h4.x, w4.x, fmaf(h4.y, w4.y, fmaf(h4.z, w4.z, fmaf(h4.w, w4.w, acc))));
        }
        logits[(size_t)(n0 + pt2) * NCLS + cls] = acc;
    }
}

extern "C" void kernel_launch(void* const* d_in, const int* in_sizes, int n_in,
                              void* d_out, int out_size, void* d_ws, size_t ws_size,
                              hipStream_t stream)
{
    (void)in_sizes; (void)n_in; (void)out_size;
    if (ws_size < (size_t)WS_NEED) return;   // R1-verified footprint (119.06 MB)

    const float* x      = (const float*)d_in[0];
    // d_in[1] = skip  : dead code in reference
    const float* px     = (const float*)d_in[2];
    const float* py     = (const float*)d_in[3];
    const float* pxyz   = (const float*)d_in[4];
    const int*   pknn   = (const int*)  d_in[5];
    // d_in[6] = num_points : unused
    const float* kp_pts = (const float*)d_in[7];
    const float* kpw    = (const float*)d_in[8];
    const float* gamma  = (const float*)d_in[9];
    const float* beta   = (const float*)d_in[10];
    const float* hw     = (const float*)d_in[11];
    const float* hb     = (const float*)d_in[12];
    float* logits = (float*)d_out;

    char* ws = (char*)d_ws;
    unsigned short* feats = (unsigned short*)(ws);
    unsigned short* kpwS  = (unsigned short*)(ws + WS_KPWT);
    float* outbuf = (float*)(ws + WS_OUT);
    float* stats  = (float*)(ws + WS_STATS);

    hipLaunchKernelGGL(zero_stats_kernel, dim3(1),     dim3(512), 0, stream, stats);
    hipLaunchKernelGGL(gs_kernel,         dim3(20000), dim3(256), 0, stream, x, px, py, feats);
    hipLaunchKernelGGL(wt_kernel,         dim3(3840),  dim3(256), 0, stream, kpw, kpwS);
    hipLaunchKernelGGL(kpconv_kernel,     dim3(1250),  dim3(256), 0, stream,
                       feats, kpwS, pknn, pxyz, kp_pts, outbuf, stats);
    hipLaunchKernelGGL(head_kernel,       dim3(5000),  dim3(256), 0, stream,
                       outbuf, stats, gamma, beta, hw, hb, logits);
}

// Round 10
// 628.283 us; speedup vs baseline: 1.8884x; 1.1507x over previous
//
#include <hip/hip_runtime.h>

// Problem constants (MyHead_67242007986918)
#define NPTS 80000      // B*NP
#define NPER 20000      // NP per batch
#define CDIM 256
#define NNB  16
#define NKP  15
#define NCLS 17
#define GSH  32
#define GSW  128

typedef __bf16 bf16x8 __attribute__((ext_vector_type(8)));
typedef float  f32x4  __attribute__((ext_vector_type(4)));

__device__ __forceinline__ unsigned short f2bf(float f){
    unsigned int u = __float_as_uint(f);
    u = u + 0x7FFFu + ((u >> 16) & 1u);     // RNE
    return (unsigned short)(u >> 16);
}
__device__ __forceinline__ unsigned int pack2(float a, float b){
    return (unsigned int)f2bf(a) | ((unsigned int)f2bf(b) << 16);
}

// async global->LDS, 16B per lane; lds dest = wave-uniform base + lane*16
#define GLD_LDS16(gsrc, ldst) \
    __builtin_amdgcn_global_load_lds((const __attribute__((address_space(1))) unsigned int*)(gsrc), \
                                     (__attribute__((address_space(3))) unsigned int*)(ldst), 16, 0, 0)

// ---------------- ws layout (R1-verified footprint, 124,848,128 B) ----------------
// feats  bf16 [NPTS][256]            :      0 .. 40,960,000
// kpwS   bf16 swizzled B (983040 el) : 40,960,000 .. 42,926,080
// outbuf f32  [NPTS][256]            : 42,926,080 .. 124,846,080
// stats  f32  [512] (sum, sumsq)     : 124,846,080 .. 124,848,128
#define WS_KPWT   40960000
#define WS_OUT    42926080
#define WS_STATS  124846080
#define WS_NEED   124848128

// swizzled B geometry: window (chunk c, pair P) holds K=32 = {k=2P+kwin} x {16 ch}
//  P<7 : block 8192 elems at (c*7+P)*8192 ; elem = (ctg*64 + q*16+m)*8 + j
//  P==7: block 4096 elems at 917504 + c*4096 (kwin0=k14 only); elem = (ctg*32 + (q&1)*16+m)*8 + j
#define B7_BASE 917504

__global__ void zero_stats_kernel(float* stats){ stats[threadIdx.x] = 0.f; }   // <<<1,512>>>

// Fused rearrange + bilinear grid-sample (border pad, align_corners=False) -> bf16 feats
__global__ __launch_bounds__(256) void gs_kernel(
    const float* __restrict__ x, const float* __restrict__ px,
    const float* __restrict__ py, unsigned short* __restrict__ feats)
{
    int gid = blockIdx.x * 256 + threadIdx.x;           // 80000*64 threads
    int n = gid >> 6;
    if (n >= NPTS) return;
    int c0 = (gid & 63) << 2;
    int b = n / NPER;
    float ix = fminf(fmaxf(((px[n] + 1.f) * (float)GSW - 1.f) * 0.5f, 0.f), (float)(GSW - 1));
    float iy = fminf(fmaxf(((py[n] + 1.f) * (float)GSH - 1.f) * 0.5f, 0.f), (float)(GSH - 1));
    float x0f = floorf(ix), y0f = floorf(iy);
    float wx = ix - x0f, wy = iy - y0f;
    int x0 = (int)x0f, y0 = (int)y0f;
    int x1 = min(x0 + 1, GSW - 1), y1 = min(y0 + 1, GSH - 1);
    const float* base = x + (size_t)b * (GSH * GSW * CDIM);
    float4 v00 = *(const float4*)(base + ((size_t)(y0 * GSW + x0)) * CDIM + c0);
    float4 v01 = *(const float4*)(base + ((size_t)(y0 * GSW + x1)) * CDIM + c0);
    float4 v10 = *(const float4*)(base + ((size_t)(y1 * GSW + x0)) * CDIM + c0);
    float4 v11 = *(const float4*)(base + ((size_t)(y1 * GSW + x1)) * CDIM + c0);
    float w00 = (1.f - wx) * (1.f - wy), w01 = wx * (1.f - wy);
    float w10 = (1.f - wx) * wy,         w11 = wx * wy;
    float r0 = v00.x * w00 + v01.x * w01 + v10.x * w10 + v11.x * w11;
    float r1 = v00.y * w00 + v01.y * w01 + v10.y * w10 + v11.y * w11;
    float r2 = v00.z * w00 + v01.z * w01 + v10.z * w10 + v11.z * w11;
    float r3 = v00.w * w00 + v01.w * w01 + v10.w * w10 + v11.w * w11;
    ushort4 o; o.x = f2bf(r0); o.y = f2bf(r1); o.z = f2bf(r2); o.w = f2bf(r3);
    *(ushort4*)(feats + (size_t)n * CDIM + c0) = o;
}

// kp_weights [k][c][d] f32 -> swizzled MFMA-B-fragment order (see geometry above).
// Reads coalesced; writes scatter into the L2-resident 2MB buffer.  (UNCHANGED)
__global__ __launch_bounds__(256) void wt_kernel(
    const float* __restrict__ kpw, unsigned short* __restrict__ kpwS)
{
    int gid = blockIdx.x * 256 + threadIdx.x;           // 15*65536 = 983,040 -> 3840 blocks
    int k = gid >> 16;
    int c = (gid >> 8) & 255;
    int d = gid & 255;
    unsigned short v = f2bf(kpw[gid]);
    int pair = k >> 1, kwin = k & 1, chunk = c >> 4, cl = c & 15;
    int kap = kwin * 16 + cl;                           // K-elem within window
    int q = kap >> 3, j = kap & 7;
    int m = d & 15, ctg = d >> 4;
    int idx;
    if (pair < 7) idx = (chunk * 7 + pair) * 8192 + (ctg * 64 + q * 16 + m) * 8 + j;
    else          idx = B7_BASE + chunk * 4096 + (ctg * 32 + q * 16 + m) * 8 + j;  // k=14 -> kwin0
    kpwS[idx] = v;
}

// Fused KPConv. R10: block = 32 points (grid 2500), 4 waves x 8 points.
// Key changes vs R7 (383us):
//  - CHUNK-PAIR staging with 64B-granule gathers: s_f [wv4][p8][e2][a16][c16]
//    (8KB/wave); each GLD call = 1 point's 16 nbrs x 64B (4 lanes/nbr).  R7's
//    32B requests had ~0% L2 hit + 1.11x line overfetch (FETCH=730MB =
//    demand*1.11; 4MB/XCD line footprint per chunk-step == L2 size -> thrash,
//    proven by R9's slower cadence yielding FETCH=385MB).  Full-line requests
//    eliminate overfetch by construction; one vmcnt drain per PAIR halves
//    stall frequency.
//  - M=32 tile: acc[2][4] (32 AGPR, -32) + wfrag[8] (-16) -> est ~158 total
//    regs <= 170 -> 3 waves/SIMD possible WITHOUT a forced cap (R3/R4's
//    mistake).  LDS 48KB -> 3 blocks/CU from LDS side too.
//  - per-parity 512B sub-slab == R7's verified layout -> tr-read formula
//    (m*8+q*128, offset p*1024+e*512) reused unchanged.
//  - R7 schedule kept: 2 barriers/chunk, hoisted B0/B1 parity pipeline,
//    setprio, stage-after-last-B-load (youngest vmem -> counted waits for B
//    never drain the stage DMAs; in-order retire).
__global__ __launch_bounds__(256, 2) void kpconv_kernel(
    const unsigned short* __restrict__ feats,
    const unsigned short* __restrict__ kpwS,
    const int*   __restrict__ pknn,
    const float* __restrict__ pxyz,
    const float* __restrict__ kp_pts,
    float* __restrict__ outbuf,
    float* __restrict__ stats)
{
    __shared__ unsigned short s_f[16384];    // 32KB [wv4][p8][e2][a16][c16] wave-private
    __shared__ unsigned short s_wf2[8192];   // 16KB [p32][k16][c16] XOR-swizzled

    int tid = threadIdx.x;
    int n0  = blockIdx.x * 32;               // 32 | NPER -> block never straddles batches
    int wv = tid >> 6, lane = tid & 63, m = lane & 15, q = lane >> 4;
    const int brow = (n0 / NPER) * NPER;     // batch row base (uniform per block)

    // ---- stager row bases: call p covers point p; lane -> (e,a,h) ----
    // lane l: e=l>>5 (chunk parity), a=(l>>1)&15 (neighbor), h=l&1 (16B half)
    // 4 lanes per neighbor cover its contiguous 64B (chunk pair) -> full-line requests
    int fb[8];
    {
        int e = lane >> 5, a = (lane >> 1) & 15, h = lane & 1;
#pragma unroll
        for (int p = 0; p < 8; p++){
            int n = n0 + wv * 8 + p;
            fb[p] = (brow + pknn[(size_t)n * NNB + a]) * CDIM + e * 16 + h * 8;
        }
    }
    // issue pair-0 stage immediately; wfrag prologue below covers the DMA latency
#pragma unroll
    for (int p = 0; p < 8; p++)
        GLD_LDS16(feats + (size_t)fb[p], (char*)s_f + wv * 8192 + p * 1024);

    // ---- w-fragments (B-operand of wf-MFMA): wfrag[p] = w[a=4q+j][k=m], j=0..3 ----
    // kappa-map: K-elem q*8+j <-> a=4q+j for j<4, zero for j>=4 (A and B agree).
    unsigned int wfrag[8][2];
    {
        int km = (m < 15) ? m : 14;                      // k=15 phantom -> w=0
        float kx = kp_pts[km * 3 + 0], ky = kp_pts[km * 3 + 1], kz = kp_pts[km * 3 + 2];
        int4 nb[8];
#pragma unroll
        for (int p = 0; p < 8; p++){
            int n = n0 + wv * 8 + p;
            nb[p] = *(const int4*)&pknn[(size_t)n * NNB + 4 * q];
        }
#pragma unroll
        for (int p = 0; p < 8; p++){
            int n = n0 + wv * 8 + p;
            float cx = pxyz[n * 3 + 0], cy = pxyz[n * 3 + 1], cz = pxyz[n * 3 + 2];
            int gi[4] = { nb[p].x, nb[p].y, nb[p].z, nb[p].w };
            float w[4];
#pragma unroll
            for (int e = 0; e < 4; e++){
                int g = brow + gi[e];
                float ex = pxyz[g * 3 + 0] - cx - kx;
                float ey = pxyz[g * 3 + 1] - cy - ky;
                float ez = pxyz[g * 3 + 2] - cz - kz;
                float d = sqrtf(ex * ex + ey * ey + ez * ez);
                w[e] = (m < 15) ? fmaxf(1.f - d * (1.f / 1.2f), 0.f) : 0.f;
            }
            wfrag[p][0] = pack2(w[0], w[1]);
            wfrag[p][1] = pack2(w[2], w[3]);
        }
    }

    f32x4 acc[2][4];
#pragma unroll
    for (int i = 0; i < 2; i++)
#pragma unroll
        for (int j = 0; j < 4; j++){ acc[i][j][0]=0.f; acc[i][j][1]=0.f; acc[i][j][2]=0.f; acc[i][j][3]=0.f; }

    // tr-b16 lane base (BYTES): R7-verified formula, per (p,e) sub-slab via imm offset
    unsigned trb;
    {
        unsigned sbase = (unsigned)(size_t)(__attribute__((address_space(3))) unsigned short*)s_f;
        trb = sbase + (unsigned)(wv * 8192 + m * 8 + q * 128);
    }
    int xr = (m & 7) << 3;                               // read-side XOR ((16rt+m)&7 == m&7)

// wf-MFMA for point p: D[c=4q+r, k=m] = sum_a f[a][c]*w[a][k]; pack -> s_wf2[row][k][c]
// row = wv*8+p (32 rows); swizzle key (row&7) == (p&7) since wv*8 % 8 == 0.
#define WF_MFMA_PACK(p) { \
        union { uint4 u; bf16x8 v; } Af, Bw; \
        Af.u = make_uint4(tr[p].x, tr[p].y, 0u, 0u); \
        Bw.u = make_uint4(wfrag[p][0], wfrag[p][1], 0u, 0u); \
        f32x4 dz; dz[0]=0.f; dz[1]=0.f; dz[2]=0.f; dz[3]=0.f; \
        f32x4 d = __builtin_amdgcn_mfma_f32_16x16x32_bf16(Af.v, Bw.v, dz, 0, 0, 0); \
        uint2 o; o.x = pack2(d[0], d[1]); o.y = pack2(d[2], d[3]); \
        *(uint2*)&s_wf2[(((wv * 8 + (p)) * 256 + m * 16 + 4 * q)) ^ (((p) & 7) << 3)] = o; }

// GEMM window P consuming register B-buffer BREG; A rows 16rt+m, rt in {0,1}
#define GEMM_WINDOW(P, BREG) { \
        bf16x8 A[2]; \
        _Pragma("unroll") \
        for (int rt = 0; rt < 2; rt++) \
            A[rt] = *(const bf16x8*)&s_wf2[(((16 * rt + m) * 256 + (2 * (P) + (q >> 1)) * 16 + (q & 1) * 8)) ^ xr]; \
        __builtin_amdgcn_s_setprio(1); \
        _Pragma("unroll") \
        for (int ct = 0; ct < 4; ct++) \
            _Pragma("unroll") \
            for (int rt = 0; rt < 2; rt++) \
                acc[rt][ct] = __builtin_amdgcn_mfma_f32_16x16x32_bf16(A[rt], BREG[ct], acc[rt][ct], 0, 0, 0); \
        __builtin_amdgcn_s_setprio(0); }

// load window Pn's B-fragments for chunk CC into BREG
#define PREFETCH_B(CC, Pn, BREG) { \
        if ((Pn) < 7){ \
            const unsigned short* bb = kpwS + ((CC) * 7 + (Pn)) * 8192 + (q * 16 + m) * 8; \
            _Pragma("unroll") \
            for (int ct = 0; ct < 4; ct++) BREG[ct] = *(const bf16x8*)(bb + (wv * 4 + ct) * 512); \
        } else { \
            const unsigned short* bb = kpwS + B7_BASE + (CC) * 4096 + ((q & 1) * 16 + m) * 8; \
            _Pragma("unroll") \
            for (int ct = 0; ct < 4; ct++) BREG[ct] = *(const bf16x8*)(bb + (wv * 4 + ct) * 256); \
        } }

    for (int cp = 0; cp < 8; cp++){
        asm volatile("s_waitcnt vmcnt(0)" ::: "memory");   // pair slab landed (wave-local)

#pragma unroll
        for (int e = 0; e < 2; e++){
            const int c = 2 * cp + e;

            // ---- wf-phase: 8 tr-reads (parity sub-slab), 4+4 counted pipeline ----
            uint2 tr[8];
#pragma unroll
            for (int p = 0; p < 8; p++)
                asm volatile("ds_read_b64_tr_b16 %0, %1 offset:%2"
                             : "=v"(tr[p]) : "v"(trb), "i"(p * 1024 + e * 512));

            asm volatile("s_waitcnt lgkmcnt(4)" ::: "memory");   // R0-3 done
            __builtin_amdgcn_sched_barrier(0);
#pragma unroll
            for (int p = 0; p < 4; p++) WF_MFMA_PACK(p)

            asm volatile("s_waitcnt lgkmcnt(4)" ::: "memory");   // R4-7 done (W0-3 in flight)
            __builtin_amdgcn_sched_barrier(0);
#pragma unroll
            for (int p = 4; p < 8; p++) WF_MFMA_PACK(p)

            // hoisted B prefetch for windows 0,1 (indep of s_wf2; hides under drain)
            bf16x8 B0[4], B1[4];
            PREFETCH_B(c, 0, B0)
            PREFETCH_B(c, 1, B1)

            asm volatile("s_waitcnt lgkmcnt(0)\ns_barrier" ::: "memory");   // s_wf2 ready

            // ---- GEMM: 8 windows, parity 2-buffer pipeline ----
            GEMM_WINDOW(0, B0)  PREFETCH_B(c, 2, B0)
            GEMM_WINDOW(1, B1)  PREFETCH_B(c, 3, B1)
            GEMM_WINDOW(2, B0)  PREFETCH_B(c, 4, B0)
            GEMM_WINDOW(3, B1)  PREFETCH_B(c, 5, B1)
            GEMM_WINDOW(4, B0)  PREFETCH_B(c, 6, B0)
            GEMM_WINDOW(5, B1)  PREFETCH_B(c, 7, B1)
            // stage(next pair) after the last B-load of the pair: youngest vmem ->
            // counted waits for B never drain it; collected at next pair's vmcnt(0)
            if (e == 1 && cp < 7){
#pragma unroll
                for (int p = 0; p < 8; p++)
                    GLD_LDS16(feats + (size_t)(fb[p] + (cp + 1) * 32), (char*)s_f + wv * 8192 + p * 1024);
            }
            GEMM_WINDOW(6, B0)
            GEMM_WINDOW(7, B1)

            asm volatile("s_waitcnt lgkmcnt(0)\ns_barrier" ::: "memory");   // s_wf2 consumed
        }
    }
#undef WF_MFMA_PACK
#undef GEMM_WINDOW
#undef PREFETCH_B

    // ---- epilogue: store fp32, fold BN partial sums via atomics ----
#pragma unroll
    for (int rt = 0; rt < 2; rt++)
#pragma unroll
        for (int ct = 0; ct < 4; ct++)
#pragma unroll
            for (int r = 0; r < 4; r++){
                int prow = 16 * rt + 4 * q + r;          // C/D: row=(lane>>4)*4+r, col=lane&15
                int d = wv * 64 + ct * 16 + m;
                outbuf[(size_t)(n0 + prow) * CDIM + d] = acc[rt][ct][r];
            }
#pragma unroll
    for (int ct = 0; ct < 4; ct++){
        float s1 = 0.f, s2 = 0.f;
#pragma unroll
        for (int rt = 0; rt < 2; rt++)
#pragma unroll
            for (int r = 0; r < 4; r++){
                float v = acc[rt][ct][r];
                s1 += v; s2 += v * v;
            }
        s1 += __shfl_xor(s1, 16); s1 += __shfl_xor(s1, 32);
        s2 += __shfl_xor(s2, 16); s2 += __shfl_xor(s2, 32);
        if (q == 0){
            int d = wv * 64 + ct * 16 + m;
            atomicAdd(&stats[d], s1);
            atomicAdd(&stats[256 + d], s2);
        }
    }
}

// BN (batch stats) + ReLU + 1x1 conv head. 16 points per block.  (UNCHANGED)
__global__ __launch_bounds__(256) void head_kernel(
    const float* __restrict__ outbuf, const float* __restrict__ stats,
    const float* __restrict__ gamma,  const float* __restrict__ beta,
    const float* __restrict__ hw,     const float* __restrict__ hb,
    float* __restrict__ logits)
{
    __shared__ float s_h[16][256];
    int tid = threadIdx.x;
    int n0 = blockIdx.x * 16;
    int pt = tid >> 4, cgr = tid & 15;
    {
        int n = n0 + pt;
        const float invN = 1.f / (float)NPTS;
#pragma unroll
        for (int j = 0; j < 16; j += 4){
            int c = cgr * 16 + j;
            float4 v  = *(const float4*)(outbuf + (size_t)n * CDIM + c);
            float4 su = *(const float4*)(stats + c);
            float4 sq = *(const float4*)(stats + 256 + c);
            float4 ga = *(const float4*)(gamma + c);
            float4 be = *(const float4*)(beta + c);
            float mean, var;
            mean = su.x * invN; var = sq.x * invN - mean * mean;
            s_h[pt][c + 0] = fmaxf(ga.x * (v.x - mean) * rsqrtf(var + 1e-5f) + be.x, 0.f);
            mean = su.y * invN; var = sq.y * invN - mean * mean;
            s_h[pt][c + 1] = fmaxf(ga.y * (v.y - mean) * rsqrtf(var + 1e-5f) + be.y, 0.f);
            mean = su.z * invN; var = sq.z * invN - mean * mean;
            s_h[pt][c + 2] = fmaxf(ga.z * (v.z - mean) * rsqrtf(var + 1e-5f) + be.z, 0.f);
            mean = su.w * invN; var = sq.w * invN - mean * mean;
            s_h[pt][c + 3] = fmaxf(ga.w * (v.w - mean) * rsqrtf(var + 1e-5f) + be.w, 0.f);
        }
    }
    __syncthreads();
    for (int idx = tid; idx < 16 * NCLS; idx += 256){
        int pt2 = idx / NCLS, cls = idx - pt2 * NCLS;
        float acc = hb[cls];
#pragma unroll 8
        for (int c = 0; c < CDIM; c += 4){
            float4 h4 = *(const float4*)&s_h[pt2][c];
            float4 w4 = *(const float4*)(hw + (size_t)cls * CDIM + c);
            acc = fmaf(h4.x, w4.x, fmaf(h4.y, w4.y, fmaf(h4.z, w4.z, fmaf(h4.w, w4.w, acc))));
        }
        logits[(size_t)(n0 + pt2) * NCLS + cls] = acc;
    }
}

extern "C" void kernel_launch(void* const* d_in, const int* in_sizes, int n_in,
                              void* d_out, int out_size, void* d_ws, size_t ws_size,
                              hipStream_t stream)
{
    (void)in_sizes; (void)n_in; (void)out_size;
    if (ws_size < (size_t)WS_NEED) return;   // R1-verified footprint (119.06 MB)

    const float* x      = (const float*)d_in[0];
    // d_in[1] = skip  : dead code in reference
    const float* px     = (const float*)d_in[2];
    const float* py     = (const float*)d_in[3];
    const float* pxyz   = (const float*)d_in[4];
    const int*   pknn   = (const int*)  d_in[5];
    // d_in[6] = num_points : unused
    const float* kp_pts = (const float*)d_in[7];
    const float* kpw    = (const float*)d_in[8];
    const float* gamma  = (const float*)d_in[9];
    const float* beta   = (const float*)d_in[10];
    const float* hw     = (const float*)d_in[11];
    const float* hb     = (const float*)d_in[12];
    float* logits = (float*)d_out;

    char* ws = (char*)d_ws;
    unsigned short* feats = (unsigned short*)(ws);
    unsigned short* kpwS  = (unsigned short*)(ws + WS_KPWT);
    float* outbuf = (float*)(ws + WS_OUT);
    float* stats  = (float*)(ws + WS_STATS);

    hipLaunchKernelGGL(zero_stats_kernel, dim3(1),     dim3(512), 0, stream, stats);
    hipLaunchKernelGGL(gs_kernel,         dim3(20000), dim3(256), 0, stream, x, px, py, feats);
    hipLaunchKernelGGL(wt_kernel,         dim3(3840),  dim3(256), 0, stream, kpw, kpwS);
    hipLaunchKernelGGL(kpconv_kernel,     dim3(2500),  dim3(256), 0, stream,
                       feats, kpwS, pknn, pxyz, kp_pts, outbuf, stats);
    hipLaunchKernelGGL(head_kernel,       dim3(5000),  dim3(256), 0, stream,
                       outbuf, stats, gamma, beta, hw, hb, logits);
}

// Round 11
// 621.914 us; speedup vs baseline: 1.9077x; 1.0102x over previous
//
#include <hip/hip_runtime.h>

// Problem constants (MyHead_67242007986918)
#define NPTS 80000      // B*NP
#define NPER 20000      // NP per batch
#define CDIM 256
#define NNB  16
#define NKP  15
#define NCLS 17
#define GSH  32
#define GSW  128

typedef __bf16 bf16x8 __attribute__((ext_vector_type(8)));
typedef float  f32x4  __attribute__((ext_vector_type(4)));

__device__ __forceinline__ unsigned short f2bf(float f){
    unsigned int u = __float_as_uint(f);
    u = u + 0x7FFFu + ((u >> 16) & 1u);     // RNE
    return (unsigned short)(u >> 16);
}
__device__ __forceinline__ unsigned int pack2(float a, float b){
    return (unsigned int)f2bf(a) | ((unsigned int)f2bf(b) << 16);
}

// async global->LDS, 16B per lane; lds dest = wave-uniform base + lane*16
#define GLD_LDS16(gsrc, ldst) \
    __builtin_amdgcn_global_load_lds((const __attribute__((address_space(1))) unsigned int*)(gsrc), \
                                     (__attribute__((address_space(3))) unsigned int*)(ldst), 16, 0, 0)

// ---------------- ws layout (R1-verified footprint, 124,848,128 B) ----------------
// feats  bf16 [NPTS][256]            :      0 .. 40,960,000
// kpwS   bf16 swizzled B (983040 el) : 40,960,000 .. 42,926,080
// outbuf f32  [NPTS][256]            : 42,926,080 .. 124,846,080
// stats  f32  [512] (sum, sumsq)     : 124,846,080 .. 124,848,128
#define WS_KPWT   40960000
#define WS_OUT    42926080
#define WS_STATS  124846080
#define WS_NEED   124848128

// swizzled B geometry: window (chunk c, pair P) holds K=32 = {k=2P+kwin} x {16 ch}
//  P<7 : block 8192 elems at (c*7+P)*8192 ; elem = (ctg*64 + q*16+m)*8 + j
//  P==7: block 4096 elems at 917504 + c*4096 (kwin0=k14 only); elem = (ctg*32 + (q&1)*16+m)*8 + j
#define B7_BASE 917504

// Fused rearrange + bilinear grid-sample (border pad, align_corners=False) -> bf16 feats
// R11: XCD-affinity block swizzle (batch <-> XCD): 20000 = 8*2500 exactly ->
// swz = (bid&7)*2500 + (bid>>3) (bijective).  Each XCD's blocks sample one
// x batch-slab (4.2MB ~ L2) -> bilinear corner reads become L2-resident.
__global__ __launch_bounds__(256) void gs_kernel(
    const float* __restrict__ x, const float* __restrict__ px,
    const float* __restrict__ py, unsigned short* __restrict__ feats)
{
    int bid = (int)(blockIdx.x & 7) * 2500 + (int)(blockIdx.x >> 3);
    int gid = bid * 256 + threadIdx.x;                  // 80000*64 threads
    int n = gid >> 6;
    if (n >= NPTS) return;
    int c0 = (gid & 63) << 2;
    int b = n / NPER;
    float ix = fminf(fmaxf(((px[n] + 1.f) * (float)GSW - 1.f) * 0.5f, 0.f), (float)(GSW - 1));
    float iy = fminf(fmaxf(((py[n] + 1.f) * (float)GSH - 1.f) * 0.5f, 0.f), (float)(GSH - 1));
    float x0f = floorf(ix), y0f = floorf(iy);
    float wx = ix - x0f, wy = iy - y0f;
    int x0 = (int)x0f, y0 = (int)y0f;
    int x1 = min(x0 + 1, GSW - 1), y1 = min(y0 + 1, GSH - 1);
    const float* base = x + (size_t)b * (GSH * GSW * CDIM);
    float4 v00 = *(const float4*)(base + ((size_t)(y0 * GSW + x0)) * CDIM + c0);
    float4 v01 = *(const float4*)(base + ((size_t)(y0 * GSW + x1)) * CDIM + c0);
    float4 v10 = *(const float4*)(base + ((size_t)(y1 * GSW + x0)) * CDIM + c0);
    float4 v11 = *(const float4*)(base + ((size_t)(y1 * GSW + x1)) * CDIM + c0);
    float w00 = (1.f - wx) * (1.f - wy), w01 = wx * (1.f - wy);
    float w10 = (1.f - wx) * wy,         w11 = wx * wy;
    float r0 = v00.x * w00 + v01.x * w01 + v10.x * w10 + v11.x * w11;
    float r1 = v00.y * w00 + v01.y * w01 + v10.y * w10 + v11.y * w11;
    float r2 = v00.z * w00 + v01.z * w01 + v10.z * w10 + v11.z * w11;
    float r3 = v00.w * w00 + v01.w * w01 + v10.w * w10 + v11.w * w11;
    ushort4 o; o.x = f2bf(r0); o.y = f2bf(r1); o.z = f2bf(r2); o.w = f2bf(r3);
    *(ushort4*)(feats + (size_t)n * CDIM + c0) = o;
}

// kp_weights [k][c][d] f32 -> swizzled MFMA-B-fragment order (see geometry above).
// R11: also zeroes stats (block 0) -> zero_stats launch removed.
__global__ __launch_bounds__(256) void wt_kernel(
    const float* __restrict__ kpw, unsigned short* __restrict__ kpwS,
    float* __restrict__ stats)
{
    if (blockIdx.x == 0){
        stats[threadIdx.x] = 0.f;
        stats[256 + threadIdx.x] = 0.f;
    }
    int gid = blockIdx.x * 256 + threadIdx.x;           // 15*65536 = 983,040 -> 3840 blocks
    int k = gid >> 16;
    int c = (gid >> 8) & 255;
    int d = gid & 255;
    unsigned short v = f2bf(kpw[gid]);
    int pair = k >> 1, kwin = k & 1, chunk = c >> 4, cl = c & 15;
    int kap = kwin * 16 + cl;                           // K-elem within window
    int q = kap >> 3, j = kap & 7;
    int m = d & 15, ctg = d >> 4;
    int idx;
    if (pair < 7) idx = (chunk * 7 + pair) * 8192 + (ctg * 64 + q * 16 + m) * 8 + j;
    else          idx = B7_BASE + chunk * 4096 + (ctg * 32 + q * 16 + m) * 8 + j;  // k=14 -> kwin0
    kpwS[idx] = v;
}

// Fused KPConv. R11 = R10-verified kernel (333us, 64B-granule pair staging,
// M=32 tile, FETCH 356MB) + XCD-affinity block swizzle:
//   Per chunk-pair the live feats line-set is 20000x64B = 1.28MB per batch
//   (5.1MB all 4).  Default round-robin dispatch gives every XCD a 5.1MB
//   working set > 4MB L2 -> thrash (the missing ~55% of L2 hits in R10's
//   FETCH=356MB vs ~41MB cold-miss floor).  Contiguous-range swizzle
//   (m204 bijective, nwg=2500: q=312,r=4) gives each XCD <=2 batches ->
//   working set <=2.6MB < 4MB -> gather slab L2-resident; latency ~600->200cy.
// Everything else byte-identical to R10.
__global__ __launch_bounds__(256, 2) void kpconv_kernel(
    const unsigned short* __restrict__ feats,
    const unsigned short* __restrict__ kpwS,
    const int*   __restrict__ pknn,
    const float* __restrict__ pxyz,
    const float* __restrict__ kp_pts,
    float* __restrict__ outbuf,
    float* __restrict__ stats)
{
    __shared__ unsigned short s_f[16384];    // 32KB [wv4][p8][e2][a16][c16] wave-private
    __shared__ unsigned short s_wf2[8192];   // 16KB [p32][k16][c16] XOR-swizzled

    int tid = threadIdx.x;
    // XCD-affinity swizzle (bijective over 2500: XCDs 0-3 get 313, 4-7 get 312)
    int xcd = (int)(blockIdx.x & 7), loc = (int)(blockIdx.x >> 3);
    int bid = (xcd < 4) ? (xcd * 313 + loc) : (4 * 313 + (xcd - 4) * 312 + loc);
    int n0  = bid * 32;                      // 32 | NPER -> block never straddles batches
    int wv = tid >> 6, lane = tid & 63, m = lane & 15, q = lane >> 4;
    const int brow = (n0 / NPER) * NPER;     // batch row base (uniform per block)

    // ---- stager row bases: call p covers point p; lane -> (e,a,h) ----
    // lane l: e=l>>5 (chunk parity), a=(l>>1)&15 (neighbor), h=l&1 (16B half)
    // 4 lanes per neighbor cover its contiguous 64B (chunk pair) -> full-line requests
    int fb[8];
    {
        int e = lane >> 5, a = (lane >> 1) & 15, h = lane & 1;
#pragma unroll
        for (int p = 0; p < 8; p++){
            int n = n0 + wv * 8 + p;
            fb[p] = (brow + pknn[(size_t)n * NNB + a]) * CDIM + e * 16 + h * 8;
        }
    }
    // issue pair-0 stage immediately; wfrag prologue below covers the DMA latency
#pragma unroll
    for (int p = 0; p < 8; p++)
        GLD_LDS16(feats + (size_t)fb[p], (char*)s_f + wv * 8192 + p * 1024);

    // ---- w-fragments (B-operand of wf-MFMA): wfrag[p] = w[a=4q+j][k=m], j=0..3 ----
    // kappa-map: K-elem q*8+j <-> a=4q+j for j<4, zero for j>=4 (A and B agree).
    unsigned int wfrag[8][2];
    {
        int km = (m < 15) ? m : 14;                      // k=15 phantom -> w=0
        float kx = kp_pts[km * 3 + 0], ky = kp_pts[km * 3 + 1], kz = kp_pts[km * 3 + 2];
        int4 nb[8];
#pragma unroll
        for (int p = 0; p < 8; p++){
            int n = n0 + wv * 8 + p;
            nb[p] = *(const int4*)&pknn[(size_t)n * NNB + 4 * q];
        }
#pragma unroll
        for (int p = 0; p < 8; p++){
            int n = n0 + wv * 8 + p;
            float cx = pxyz[n * 3 + 0], cy = pxyz[n * 3 + 1], cz = pxyz[n * 3 + 2];
            int gi[4] = { nb[p].x, nb[p].y, nb[p].z, nb[p].w };
            float w[4];
#pragma unroll
            for (int e = 0; e < 4; e++){
                int g = brow + gi[e];
                float ex = pxyz[g * 3 + 0] - cx - kx;
                float ey = pxyz[g * 3 + 1] - cy - ky;
                float ez = pxyz[g * 3 + 2] - cz - kz;
                float d = sqrtf(ex * ex + ey * ey + ez * ez);
                w[e] = (m < 15) ? fmaxf(1.f - d * (1.f / 1.2f), 0.f) : 0.f;
            }
            wfrag[p][0] = pack2(w[0], w[1]);
            wfrag[p][1] = pack2(w[2], w[3]);
        }
    }

    f32x4 acc[2][4];
#pragma unroll
    for (int i = 0; i < 2; i++)
#pragma unroll
        for (int j = 0; j < 4; j++){ acc[i][j][0]=0.f; acc[i][j][1]=0.f; acc[i][j][2]=0.f; acc[i][j][3]=0.f; }

    // tr-b16 lane base (BYTES): R7-verified formula, per (p,e) sub-slab via imm offset
    unsigned trb;
    {
        unsigned sbase = (unsigned)(size_t)(__attribute__((address_space(3))) unsigned short*)s_f;
        trb = sbase + (unsigned)(wv * 8192 + m * 8 + q * 128);
    }
    int xr = (m & 7) << 3;                               // read-side XOR ((16rt+m)&7 == m&7)

// wf-MFMA for point p: D[c=4q+r, k=m] = sum_a f[a][c]*w[a][k]; pack -> s_wf2[row][k][c]
// row = wv*8+p (32 rows); swizzle key (row&7) == (p&7) since wv*8 % 8 == 0.
#define WF_MFMA_PACK(p) { \
        union { uint4 u; bf16x8 v; } Af, Bw; \
        Af.u = make_uint4(tr[p].x, tr[p].y, 0u, 0u); \
        Bw.u = make_uint4(wfrag[p][0], wfrag[p][1], 0u, 0u); \
        f32x4 dz; dz[0]=0.f; dz[1]=0.f; dz[2]=0.f; dz[3]=0.f; \
        f32x4 d = __builtin_amdgcn_mfma_f32_16x16x32_bf16(Af.v, Bw.v, dz, 0, 0, 0); \
        uint2 o; o.x = pack2(d[0], d[1]); o.y = pack2(d[2], d[3]); \
        *(uint2*)&s_wf2[(((wv * 8 + (p)) * 256 + m * 16 + 4 * q)) ^ (((p) & 7) << 3)] = o; }

// GEMM window P consuming register B-buffer BREG; A rows 16rt+m, rt in {0,1}
#define GEMM_WINDOW(P, BREG) { \
        bf16x8 A[2]; \
        _Pragma("unroll") \
        for (int rt = 0; rt < 2; rt++) \
            A[rt] = *(const bf16x8*)&s_wf2[(((16 * rt + m) * 256 + (2 * (P) + (q >> 1)) * 16 + (q & 1) * 8)) ^ xr]; \
        __builtin_amdgcn_s_setprio(1); \
        _Pragma("unroll") \
        for (int ct = 0; ct < 4; ct++) \
            _Pragma("unroll") \
            for (int rt = 0; rt < 2; rt++) \
                acc[rt][ct] = __builtin_amdgcn_mfma_f32_16x16x32_bf16(A[rt], BREG[ct], acc[rt][ct], 0, 0, 0); \
        __builtin_amdgcn_s_setprio(0); }

// load window Pn's B-fragments for chunk CC into BREG
#define PREFETCH_B(CC, Pn, BREG) { \
        if ((Pn) < 7){ \
            const unsigned short* bb = kpwS + ((CC) * 7 + (Pn)) * 8192 + (q * 16 + m) * 8; \
            _Pragma("unroll") \
            for (int ct = 0; ct < 4; ct++) BREG[ct] = *(const bf16x8*)(bb + (wv * 4 + ct) * 512); \
        } else { \
            const unsigned short* bb = kpwS + B7_BASE + (CC) * 4096 + ((q & 1) * 16 + m) * 8; \
            _Pragma("unroll") \
            for (int ct = 0; ct < 4; ct++) BREG[ct] = *(const bf16x8*)(bb + (wv * 4 + ct) * 256); \
        } }

    for (int cp = 0; cp < 8; cp++){
        asm volatile("s_waitcnt vmcnt(0)" ::: "memory");   // pair slab landed (wave-local)

#pragma unroll
        for (int e = 0; e < 2; e++){
            const int c = 2 * cp + e;

            // ---- wf-phase: 8 tr-reads (parity sub-slab), 4+4 counted pipeline ----
            uint2 tr[8];
#pragma unroll
            for (int p = 0; p < 8; p++)
                asm volatile("ds_read_b64_tr_b16 %0, %1 offset:%2"
                             : "=v"(tr[p]) : "v"(trb), "i"(p * 1024 + e * 512));

            asm volatile("s_waitcnt lgkmcnt(4)" ::: "memory");   // R0-3 done
            __builtin_amdgcn_sched_barrier(0);
#pragma unroll
            for (int p = 0; p < 4; p++) WF_MFMA_PACK(p)

            asm volatile("s_waitcnt lgkmcnt(4)" ::: "memory");   // R4-7 done (W0-3 in flight)
            __builtin_amdgcn_sched_barrier(0);
#pragma unroll
            for (int p = 4; p < 8; p++) WF_MFMA_PACK(p)

            // hoisted B prefetch for windows 0,1 (indep of s_wf2; hides under drain)
            bf16x8 B0[4], B1[4];
            PREFETCH_B(c, 0, B0)
            PREFETCH_B(c, 1, B1)

            asm volatile("s_waitcnt lgkmcnt(0)\ns_barrier" ::: "memory");   // s_wf2 ready

            // ---- GEMM: 8 windows, parity 2-buffer pipeline ----
            GEMM_WINDOW(0, B0)  PREFETCH_B(c, 2, B0)
            GEMM_WINDOW(1, B1)  PREFETCH_B(c, 3, B1)
            GEMM_WINDOW(2, B0)  PREFETCH_B(c, 4, B0)
            GEMM_WINDOW(3, B1)  PREFETCH_B(c, 5, B1)
            GEMM_WINDOW(4, B0)  PREFETCH_B(c, 6, B0)
            GEMM_WINDOW(5, B1)  PREFETCH_B(c, 7, B1)
            // stage(next pair) after the last B-load of the pair: youngest vmem ->
            // counted waits for B never drain it; collected at next pair's vmcnt(0)
            if (e == 1 && cp < 7){
#pragma unroll
                for (int p = 0; p < 8; p++)
                    GLD_LDS16(feats + (size_t)(fb[p] + (cp + 1) * 32), (char*)s_f + wv * 8192 + p * 1024);
            }
            GEMM_WINDOW(6, B0)
            GEMM_WINDOW(7, B1)

            asm volatile("s_waitcnt lgkmcnt(0)\ns_barrier" ::: "memory");   // s_wf2 consumed
        }
    }
#undef WF_MFMA_PACK
#undef GEMM_WINDOW
#undef PREFETCH_B

    // ---- epilogue: store fp32, fold BN partial sums via atomics ----
#pragma unroll
    for (int rt = 0; rt < 2; rt++)
#pragma unroll
        for (int ct = 0; ct < 4; ct++)
#pragma unroll
            for (int r = 0; r < 4; r++){
                int prow = 16 * rt + 4 * q + r;          // C/D: row=(lane>>4)*4+r, col=lane&15
                int d = wv * 64 + ct * 16 + m;
                outbuf[(size_t)(n0 + prow) * CDIM + d] = acc[rt][ct][r];
            }
#pragma unroll
    for (int ct = 0; ct < 4; ct++){
        float s1 = 0.f, s2 = 0.f;
#pragma unroll
        for (int rt = 0; rt < 2; rt++)
#pragma unroll
            for (int r = 0; r < 4; r++){
                float v = acc[rt][ct][r];
                s1 += v; s2 += v * v;
            }
        s1 += __shfl_xor(s1, 16); s1 += __shfl_xor(s1, 32);
        s2 += __shfl_xor(s2, 16); s2 += __shfl_xor(s2, 32);
        if (q == 0){
            int d = wv * 64 + ct * 16 + m;
            atomicAdd(&stats[d], s1);
            atomicAdd(&stats[256 + d], s2);
        }
    }
}

// BN (batch stats) + ReLU + 1x1 conv head. 16 points per block.  (UNCHANGED)
__global__ __launch_bounds__(256) void head_kernel(
    const float* __restrict__ outbuf, const float* __restrict__ stats,
    const float* __restrict__ gamma,  const float* __restrict__ beta,
    const float* __restrict__ hw,     const float* __restrict__ hb,
    float* __restrict__ logits)
{
    __shared__ float s_h[16][256];
    int tid = threadIdx.x;
    int n0 = blockIdx.x * 16;
    int pt = tid >> 4, cgr = tid & 15;
    {
        int n = n0 + pt;
        const float invN = 1.f / (float)NPTS;
#pragma unroll
        for (int j = 0; j < 16; j += 4){
            int c = cgr * 16 + j;
            float4 v  = *(const float4*)(outbuf + (size_t)n * CDIM + c);
            float4 su = *(const float4*)(stats + c);
            float4 sq = *(const float4*)(stats + 256 + c);
            float4 ga = *(const float4*)(gamma + c);
            float4 be = *(const float4*)(beta + c);
            float mean, var;
            mean = su.x * invN; var = sq.x * invN - mean * mean;
            s_h[pt][c + 0] = fmaxf(ga.x * (v.x - mean) * rsqrtf(var + 1e-5f) + be.x, 0.f);
            mean = su.y * invN; var = sq.y * invN - mean * mean;
            s_h[pt][c + 1] = fmaxf(ga.y * (v.y - mean) * rsqrtf(var + 1e-5f) + be.y, 0.f);
            mean = su.z * invN; var = sq.z * invN - mean * mean;
            s_h[pt][c + 2] = fmaxf(ga.z * (v.z - mean) * rsqrtf(var + 1e-5f) + be.z, 0.f);
            mean = su.w * invN; var = sq.w * invN - mean * mean;
            s_h[pt][c + 3] = fmaxf(ga.w * (v.w - mean) * rsqrtf(var + 1e-5f) + be.w, 0.f);
        }
    }
    __syncthreads();
    for (int idx = tid; idx < 16 * NCLS; idx += 256){
        int pt2 = idx / NCLS, cls = idx - pt2 * NCLS;
        float acc = hb[cls];
#pragma unroll 8
        for (int c = 0; c < CDIM; c += 4){
            float4 h4 = *(const float4*)&s_h[pt2][c];
            float4 w4 = *(const float4*)(hw + (size_t)cls * CDIM + c);
            acc = fmaf(h4.x, w4.x, fmaf(h4.y, w4.y, fmaf(h4.z, w4.z, fmaf(h4.w, w4.w, acc))));
        }
        logits[(size_t)(n0 + pt2) * NCLS + cls] = acc;
    }
}

extern "C" void kernel_launch(void* const* d_in, const int* in_sizes, int n_in,
                              void* d_out, int out_size, void* d_ws, size_t ws_size,
                              hipStream_t stream)
{
    (void)in_sizes; (void)n_in; (void)out_size;
    if (ws_size < (size_t)WS_NEED) return;   // R1-verified footprint (119.06 MB)

    const float* x      = (const float*)d_in[0];
    // d_in[1] = skip  : dead code in reference
    const float* px     = (const float*)d_in[2];
    const float* py     = (const float*)d_in[3];
    const float* pxyz   = (const float*)d_in[4];
    const int*   pknn   = (const int*)  d_in[5];
    // d_in[6] = num_points : unused
    const float* kp_pts = (const float*)d_in[7];
    const float* kpw    = (const float*)d_in[8];
    const float* gamma  = (const float*)d_in[9];
    const float* beta   = (const float*)d_in[10];
    const float* hw     = (const float*)d_in[11];
    const float* hb     = (const float*)d_in[12];
    float* logits = (float*)d_out;

    char* ws = (char*)d_ws;
    unsigned short* feats = (unsigned short*)(ws);
    unsigned short* kpwS  = (unsigned short*)(ws + WS_KPWT);
    float* outbuf = (float*)(ws + WS_OUT);
    float* stats  = (float*)(ws + WS_STATS);

    hipLaunchKernelGGL(gs_kernel,         dim3(20000), dim3(256), 0, stream, x, px, py, feats);
    hipLaunchKernelGGL(wt_kernel,         dim3(3840),  dim3(256), 0, stream, kpw, kpwS, stats);
    hipLaunchKernelGGL(kpconv_kernel,     dim3(2500),  dim3(256), 0, stream,
                       feats, kpwS, pknn, pxyz, kp_pts, outbuf, stats);
    hipLaunchKernelGGL(head_kernel,       dim3(5000),  dim3(256), 0, stream,
                       outbuf, stats, gamma, beta, hw, hb, logits);
}